// Round 1
// baseline (332.669 us; speedup 1.0000x reference)
//
#include <hip/hip_runtime.h>
#include <hip/hip_bf16.h>

#define D_FEAT 128

typedef short short8 __attribute__((ext_vector_type(8)));
typedef float floatx4 __attribute__((ext_vector_type(4)));

// Kernel 1: W [128x128] fp32 row-major -> Wt [n][k] bf16 (transposed), so the
// MFMA B-fragment (8 consecutive k for fixed n) is a contiguous 16B load.
__global__ void wprep_kernel(const float* __restrict__ W,
                             __hip_bfloat16* __restrict__ Wt) {
    int tid = blockIdx.x * blockDim.x + threadIdx.x;   // 0..16383
    int n = tid & (D_FEAT - 1);
    int k = tid >> 7;
    // read coalesced (consecutive n), write strided (tiny matrix, don't care)
    Wt[n * D_FEAT + k] = __float2bfloat16(W[k * D_FEAT + n]);
}

// Kernel 2: CSR aggregation. One block (128 threads) per destination row,
// thread k owns feature k. fp32 accumulate, bf16 store to X' in ws.
__global__ void agg_kernel(const float* __restrict__ X,
                           const int* __restrict__ row_pointers,
                           const int* __restrict__ column_index,
                           __hip_bfloat16* __restrict__ Xp) {
    int r = blockIdx.x;
    int k = threadIdx.x;                 // 0..127
    int e0 = row_pointers[r];
    int e1 = row_pointers[r + 1];
    float acc = 0.0f;
    for (int e = e0; e < e1; ++e) {
        int c = column_index[e];         // broadcast across block via cache
        acc += X[(size_t)c * D_FEAT + k];   // 512B coalesced per edge
    }
    Xp[(size_t)r * D_FEAT + k] = __float2bfloat16(acc);
}

// Kernel 3: out = X' @ W via bf16 MFMA, fp32 accumulate.
// Grid: one block per 16-row window; block = 512 threads = 8 waves;
// wave w computes C-tile rows[0..15] x cols[16w..16w+15] with 4 MFMAs (K=128).
// Fragment layouts (HW-verified, guide §3):
//   A: m = lane&15, k = (lane>>4)*8 + j   (8 contiguous bf16 of row m)
//   B: n = lane&15, k = (lane>>4)*8 + j   (8 contiguous bf16 of Wt row n)
//   C: col = lane&15, row = (lane>>4)*4 + reg
__global__ __launch_bounds__(512)
void gemm_kernel(const __hip_bfloat16* __restrict__ Xp,
                 const __hip_bfloat16* __restrict__ Wt,
                 float* __restrict__ out) {
    int win  = blockIdx.x;
    int wave = threadIdx.x >> 6;         // 0..7 -> N-tile
    int lane = threadIdx.x & 63;
    int m    = lane & 15;
    int quad = lane >> 4;

    const __hip_bfloat16* arow = Xp + ((size_t)win * 16 + m) * D_FEAT + quad * 8;
    const __hip_bfloat16* brow = Wt + ((size_t)(wave * 16 + m)) * D_FEAT + quad * 8;

    floatx4 acc = {0.f, 0.f, 0.f, 0.f};
#pragma unroll
    for (int s = 0; s < 4; ++s) {
        short8 a = *(const short8*)(arow + s * 32);
        short8 b = *(const short8*)(brow + s * 32);
        acc = __builtin_amdgcn_mfma_f32_16x16x32_bf16(a, b, acc, 0, 0, 0);
    }

    int col     = wave * 16 + m;
    int rowbase = quad * 4;
#pragma unroll
    for (int i = 0; i < 4; ++i) {
        out[((size_t)win * 16 + rowbase + i) * D_FEAT + col] = acc[i];
    }
}

extern "C" void kernel_launch(void* const* d_in, const int* in_sizes, int n_in,
                              void* d_out, int out_size, void* d_ws, size_t ws_size,
                              hipStream_t stream) {
    const float* X        = (const float*)d_in[0];   // [N, 128] fp32
    const float* W        = (const float*)d_in[1];   // [128, 128] fp32
    const int* row_ptrs   = (const int*)d_in[2];     // [N+1]
    const int* col_index  = (const int*)d_in[3];     // [E]
    // d_in[4..9]: layout metadata, unused (does not affect math)

    float* out = (float*)d_out;
    const int N = in_sizes[2] - 1;                   // 100000

    char* ws = (char*)d_ws;
    __hip_bfloat16* Wt = (__hip_bfloat16*)ws;                 // 128*128 bf16 = 32KB
    __hip_bfloat16* Xp = (__hip_bfloat16*)(ws + 32768);       // N*128 bf16 = 25.6MB

    // 1) transpose+convert W
    wprep_kernel<<<64, 256, 0, stream>>>(W, Wt);
    // 2) CSR aggregation into bf16 X'
    agg_kernel<<<N, D_FEAT, 0, stream>>>(X, row_ptrs, col_index, Xp);
    // 3) MFMA GEMM (N divisible by 16: 100000 = 6250*16)
    gemm_kernel<<<N / 16, 512, 0, stream>>>(Xp, Wt, out);
}

// Round 2
// 250.291 us; speedup vs baseline: 1.3291x; 1.3291x over previous
//
#include <hip/hip_runtime.h>
#include <hip/hip_bf16.h>

#define D_FEAT 128

typedef short short8 __attribute__((ext_vector_type(8)));
typedef float floatx4 __attribute__((ext_vector_type(4)));

__device__ __forceinline__ short f2bf(float f) {
    __hip_bfloat16 h = __float2bfloat16(f);   // RNE
    return *reinterpret_cast<short*>(&h);
}
__device__ __forceinline__ float bf_lo(unsigned u) {
    unsigned v = u << 16;
    return *reinterpret_cast<float*>(&v);
}
__device__ __forceinline__ float bf_hi(unsigned u) {
    unsigned v = u & 0xffff0000u;
    return *reinterpret_cast<float*>(&v);
}

// Kernel 1: W [128x128] fp32 row-major -> Wt [n][k] bf16 (transposed) so the
// MFMA B-fragment (8 consecutive k for fixed n) is one contiguous 16B load.
__global__ void wprep_kernel(const float* __restrict__ W,
                             __hip_bfloat16* __restrict__ Wt) {
    int tid = blockIdx.x * blockDim.x + threadIdx.x;   // 0..16383
    int n = tid & (D_FEAT - 1);
    int k = tid >> 7;
    Wt[n * D_FEAT + k] = __float2bfloat16(W[k * D_FEAT + n]);
}

// Kernel 2: Y = X @ W  (segment_sum commutes with the linear map, so we GEMM
// FIRST and gather bf16 Y afterwards -> halves gather bytes vs fp32 X).
// One block per 16-row window; 8 waves; wave w does cols [16w,16w+16).
// Fragment layouts (HW-verified, guide §3):
//   A: m = lane&15, k = quad*8 + j   B: n = lane&15, k = quad*8 + j
//   C: col = lane&15, row = quad*4 + reg
__global__ __launch_bounds__(512)
void gemm_kernel(const float* __restrict__ X,
                 const __hip_bfloat16* __restrict__ Wt,
                 __hip_bfloat16* __restrict__ Yb) {
    int win  = blockIdx.x;
    int wave = threadIdx.x >> 6;
    int lane = threadIdx.x & 63;
    int m    = lane & 15;
    int quad = lane >> 4;

    const float* arow = X + ((size_t)win * 16 + m) * D_FEAT + quad * 8;
    const __hip_bfloat16* brow =
        Wt + ((size_t)(wave * 16 + m)) * D_FEAT + quad * 8;

    floatx4 acc = {0.f, 0.f, 0.f, 0.f};
#pragma unroll
    for (int s = 0; s < 4; ++s) {
        float4 f0 = *(const float4*)(arow + s * 32);
        float4 f1 = *(const float4*)(arow + s * 32 + 4);
        short8 a;
        a[0] = f2bf(f0.x); a[1] = f2bf(f0.y); a[2] = f2bf(f0.z); a[3] = f2bf(f0.w);
        a[4] = f2bf(f1.x); a[5] = f2bf(f1.y); a[6] = f2bf(f1.z); a[7] = f2bf(f1.w);
        short8 b = *(const short8*)(brow + s * 32);
        acc = __builtin_amdgcn_mfma_f32_16x16x32_bf16(a, b, acc, 0, 0, 0);
    }

    int col     = wave * 16 + m;
    int rowbase = quad * 4;
#pragma unroll
    for (int i = 0; i < 4; ++i) {
        Yb[((size_t)win * 16 + rowbase + i) * D_FEAT + col] =
            __float2bfloat16(acc[i]);
    }
}

// Kernel 3: out[r,:] = sum_{e in row r} Yb[col[e],:]  (fp32 accumulate).
// One wave per row (lane owns features {2*lane, 2*lane+1} via one dword),
// 4 rows per 256-thread block. Edge loop unrolled 4-deep for MLP.
__global__ __launch_bounds__(256)
void agg_kernel(const unsigned int* __restrict__ Yb,   // [N][64] dwords
                const int* __restrict__ row_pointers,
                const int* __restrict__ column_index,
                float2* __restrict__ out) {             // [N][64] float2
    int wave = threadIdx.x >> 6;
    int lane = threadIdx.x & 63;
    int r    = blockIdx.x * 4 + wave;

    int e0 = row_pointers[r];
    int e1 = row_pointers[r + 1];
    float a0 = 0.f, a1 = 0.f;
    float b0 = 0.f, b1 = 0.f;

    int e = e0;
    for (; e + 4 <= e1; e += 4) {
        int c0 = column_index[e];
        int c1 = column_index[e + 1];
        int c2 = column_index[e + 2];
        int c3 = column_index[e + 3];
        unsigned u0 = Yb[(size_t)c0 * 64 + lane];
        unsigned u1 = Yb[(size_t)c1 * 64 + lane];
        unsigned u2 = Yb[(size_t)c2 * 64 + lane];
        unsigned u3 = Yb[(size_t)c3 * 64 + lane];
        a0 += bf_lo(u0); a1 += bf_hi(u0);
        b0 += bf_lo(u1); b1 += bf_hi(u1);
        a0 += bf_lo(u2); a1 += bf_hi(u2);
        b0 += bf_lo(u3); b1 += bf_hi(u3);
    }
    for (; e < e1; ++e) {
        int c = column_index[e];
        unsigned u = Yb[(size_t)c * 64 + lane];
        a0 += bf_lo(u); a1 += bf_hi(u);
    }

    float2 res;
    res.x = a0 + b0;
    res.y = a1 + b1;
    out[(size_t)r * 64 + lane] = res;
}

extern "C" void kernel_launch(void* const* d_in, const int* in_sizes, int n_in,
                              void* d_out, int out_size, void* d_ws, size_t ws_size,
                              hipStream_t stream) {
    const float* X       = (const float*)d_in[0];   // [N, 128] fp32
    const float* W       = (const float*)d_in[1];   // [128, 128] fp32
    const int* row_ptrs  = (const int*)d_in[2];     // [N+1]
    const int* col_index = (const int*)d_in[3];     // [E]

    float* out = (float*)d_out;
    const int N = in_sizes[2] - 1;                  // 100000

    char* ws = (char*)d_ws;
    __hip_bfloat16* Wt = (__hip_bfloat16*)ws;            // 32 KB
    __hip_bfloat16* Yb = (__hip_bfloat16*)(ws + 32768);  // N*128 bf16 = 25.6 MB

    // 1) transpose+convert W
    wprep_kernel<<<64, 256, 0, stream>>>(W, Wt);
    // 2) Y = X @ W, stored bf16 (N = 6250*16)
    gemm_kernel<<<N / 16, 512, 0, stream>>>(X, Wt, Yb);
    // 3) gather+segment-sum over bf16 Y (N = 25000*4)
    agg_kernel<<<N / 4, 256, 0, stream>>>((const unsigned int*)Yb, row_ptrs,
                                          col_index, (float2*)out);
}

// Round 3
// 214.394 us; speedup vs baseline: 1.5517x; 1.1674x over previous
//
#include <hip/hip_runtime.h>
#include <hip/hip_bf16.h>

typedef short short8 __attribute__((ext_vector_type(8)));
typedef float floatx4 __attribute__((ext_vector_type(4)));

__device__ __forceinline__ unsigned short f2bf_u(float f) {
    __hip_bfloat16 h = __float2bfloat16(f);   // RNE
    return *reinterpret_cast<unsigned short*>(&h);
}

// accumulate a bf16 pair (packed in a dword) into a float2 accumulator
__device__ __forceinline__ void acc2(float2& acc, unsigned u) {
    unsigned lo = u << 16;
    unsigned hi = u & 0xffff0000u;
    acc.x += __builtin_bit_cast(float, lo);
    acc.y += __builtin_bit_cast(float, hi);
}

// Kernel 1: W [128x128] fp32 row-major -> Wt [n][k] bf16 (transposed) so the
// MFMA A-fragment (8 consecutive k for fixed n) is one contiguous 16B load.
__global__ void wprep_kernel(const float* __restrict__ W,
                             __hip_bfloat16* __restrict__ Wt) {
    int tid = blockIdx.x * blockDim.x + threadIdx.x;   // 0..16383
    int n = tid & 127;
    int k = tid >> 7;
    Wt[n * 128 + k] = __float2bfloat16(W[k * 128 + n]);
}

// Kernel 2: Y = X @ W, bf16 out. 32 rows/block, 256 threads (4 waves).
// - X tile staged fp32->bf16 into XOR-swizzled LDS (conflict-free b128 reads)
// - MFMA with SWAPPED operands (A=Wt rows, B=X rows): D lane mapping becomes
//   row = lane&15 (X row), cols = quad*4+reg (4 consecutive!) -> 8B stores.
__global__ __launch_bounds__(256)
void gemm_kernel(const float* __restrict__ X,
                 const __hip_bfloat16* __restrict__ Wt,
                 char* __restrict__ Yb) {
    __shared__ unsigned short As[32 * 128];   // 8 KB, XOR-swizzled

    int tid = threadIdx.x;
    size_t rowbase = (size_t)blockIdx.x * 32;

    // stage: 8 rows/iter, 32 threads/row, float4 each -> 4 bf16 (8B) to LDS
    {
        int rr = tid >> 5;          // 0..7
        int c4 = (tid & 31) * 4;    // 0..124
        int kb = c4 >> 3;           // 8-elem block index 0..15
        int ko = c4 & 7;            // 0 or 4
#pragma unroll
        for (int it = 0; it < 4; ++it) {
            int row = it * 8 + rr;
            float4 f = *(const float4*)(X + (rowbase + row) * 128 + c4);
            uint2 p;
            p.x = (unsigned)f2bf_u(f.x) | ((unsigned)f2bf_u(f.y) << 16);
            p.y = (unsigned)f2bf_u(f.z) | ((unsigned)f2bf_u(f.w) << 16);
            // XOR swizzle on 8-elem blocks: read side lands conflict-free
            *(uint2*)(As + row * 128 + ((kb ^ (row & 15)) << 3) + ko) = p;
        }
    }
    __syncthreads();

    int wv   = tid >> 6;        // 0..3
    int lane = tid & 63;
    int m16  = lane & 15;       // output row within row-tile
    int quad = lane >> 4;
    int rt   = wv & 1;          // row-tile (16 rows)
    int ctb  = (wv >> 1) * 4;   // col-tile base (4 tiles of 16 cols)

    floatx4 acc[4] = {{0,0,0,0},{0,0,0,0},{0,0,0,0},{0,0,0,0}};
    int arow = rt * 16 + m16;   // X row within block tile; arow&15 == m16
#pragma unroll
    for (int s = 0; s < 4; ++s) {
        int kb = quad + s * 4;  // 8-elem k-block
        short8 bfrag = *(const short8*)(As + arow * 128 + ((kb ^ m16) << 3));
#pragma unroll
        for (int t = 0; t < 4; ++t) {
            short8 afrag = *(const short8*)(Wt + ((ctb + t) * 16 + m16) * 128 +
                                            quad * 8 + s * 32);
            acc[t] = __builtin_amdgcn_mfma_f32_16x16x32_bf16(afrag, bfrag,
                                                             acc[t], 0, 0, 0);
        }
    }

    // epilogue: lane holds Y[orow][ocol..ocol+3] -> pack 4 bf16, 8B store
    size_t orow = rowbase + rt * 16 + m16;
#pragma unroll
    for (int t = 0; t < 4; ++t) {
        int ocol = (ctb + t) * 16 + quad * 4;
        uint2 p;
        p.x = (unsigned)f2bf_u(acc[t][0]) | ((unsigned)f2bf_u(acc[t][1]) << 16);
        p.y = (unsigned)f2bf_u(acc[t][2]) | ((unsigned)f2bf_u(acc[t][3]) << 16);
        *(uint2*)(Yb + orow * 256 + ocol * 2) = p;
    }
}

// Kernel 3: out[r,:] = sum_{e in row r} Yb[col[e],:]  (fp32 accumulate).
// 1 wave/row, 4 rows/block. 2 edges per gather instr (dwordx2/lane, 32
// lanes/row => 512B coalesced), 8 edges in flight per unrolled iter.
__global__ __launch_bounds__(256)
void agg_kernel(const char* __restrict__ Yb,
                const int* __restrict__ row_pointers,
                const int* __restrict__ column_index,
                float* __restrict__ out) {
    int lane = threadIdx.x & 63;
    int r    = blockIdx.x * 4 + (threadIdx.x >> 6);
    int sub  = lane >> 5;        // which of the 2 edges in a gather
    int fg   = lane & 31;        // feature group: features fg*4 .. fg*4+3
    int foff = fg * 8;           // byte offset within a 256B row

    int e0 = row_pointers[r];
    int e1 = row_pointers[r + 1];

    float2 a0 = {0.f, 0.f}, a1 = {0.f, 0.f};

    int e = e0;
    int efull = e0 + ((e1 - e0) & ~7);
    for (; e < efull; e += 8) {
        int c0 = column_index[e + sub];
        int c1 = column_index[e + 2 + sub];
        int c2 = column_index[e + 4 + sub];
        int c3 = column_index[e + 6 + sub];
        uint2 u0 = *(const uint2*)(Yb + (size_t)c0 * 256 + foff);
        uint2 u1 = *(const uint2*)(Yb + (size_t)c1 * 256 + foff);
        uint2 u2 = *(const uint2*)(Yb + (size_t)c2 * 256 + foff);
        uint2 u3 = *(const uint2*)(Yb + (size_t)c3 * 256 + foff);
        acc2(a0, u0.x); acc2(a1, u0.y);
        acc2(a0, u1.x); acc2(a1, u1.y);
        acc2(a0, u2.x); acc2(a1, u2.y);
        acc2(a0, u3.x); acc2(a1, u3.y);
    }
    for (; e < e1; e += 2) {
        int idx   = e + sub;
        bool valid = idx < e1;
        int c = column_index[valid ? idx : e1 - 1];
        uint2 u = *(const uint2*)(Yb + (size_t)c * 256 + foff);
        if (!valid) { u.x = 0u; u.y = 0u; }
        acc2(a0, u.x); acc2(a1, u.y);
    }

    // combine the two edge-subsets (xor-32), then lanes 0-31 store float4
    a0.x += __shfl_xor(a0.x, 32);
    a0.y += __shfl_xor(a0.y, 32);
    a1.x += __shfl_xor(a1.x, 32);
    a1.y += __shfl_xor(a1.y, 32);

    if (sub == 0) {
        float4 v = {a0.x, a0.y, a1.x, a1.y};
        *(float4*)(out + (size_t)r * 128 + fg * 4) = v;
    }
}

extern "C" void kernel_launch(void* const* d_in, const int* in_sizes, int n_in,
                              void* d_out, int out_size, void* d_ws, size_t ws_size,
                              hipStream_t stream) {
    const float* X       = (const float*)d_in[0];   // [N, 128] fp32
    const float* W       = (const float*)d_in[1];   // [128, 128] fp32
    const int* row_ptrs  = (const int*)d_in[2];     // [N+1]
    const int* col_index = (const int*)d_in[3];     // [E]

    float* out = (float*)d_out;
    const int N = in_sizes[2] - 1;                  // 100000

    char* ws = (char*)d_ws;
    __hip_bfloat16* Wt = (__hip_bfloat16*)ws;       // 32 KB
    char* Yb = ws + 32768;                          // N*128 bf16 = 25.6 MB

    wprep_kernel<<<64, 256, 0, stream>>>(W, Wt);
    gemm_kernel<<<N / 32, 256, 0, stream>>>(X, Wt, Yb);           // N=3125*32
    agg_kernel<<<N / 4, 256, 0, stream>>>(Yb, row_ptrs, col_index, out);
}

// Round 6
// 209.858 us; speedup vs baseline: 1.5852x; 1.0216x over previous
//
#include <hip/hip_runtime.h>
#include <hip/hip_bf16.h>

typedef short short8 __attribute__((ext_vector_type(8)));
typedef float floatx4 __attribute__((ext_vector_type(4)));
typedef unsigned int uintx4 __attribute__((ext_vector_type(4)));
typedef unsigned int uintx2 __attribute__((ext_vector_type(2)));

__device__ __forceinline__ unsigned short f2bf_u(float f) {
    __hip_bfloat16 h = __float2bfloat16(f);   // RNE
    return *reinterpret_cast<unsigned short*>(&h);
}

// bf16 pair packed in a dword -> two fp32 values
__device__ __forceinline__ float bflo(unsigned u) {
    unsigned l = u << 16;
    return __builtin_bit_cast(float, l);
}
__device__ __forceinline__ float bfhi(unsigned u) {
    unsigned h = u & 0xffff0000u;
    return __builtin_bit_cast(float, h);
}
// uintx4 = 8 bf16 features -> accA (features 0..3), accB (features 4..7)
__device__ __forceinline__ void acc_u4(floatx4& A, floatx4& B, uintx4 u) {
    A.x += bflo(u.x); A.y += bfhi(u.x);
    A.z += bflo(u.y); A.w += bfhi(u.y);
    B.x += bflo(u.z); B.y += bfhi(u.z);
    B.z += bflo(u.w); B.w += bfhi(u.w);
}

// Kernel 1: W [128x128] fp32 row-major -> Wt [n][k] bf16 (transposed) so the
// MFMA A-fragment (8 consecutive k for fixed n) is one contiguous 16B load.
__global__ void wprep_kernel(const float* __restrict__ W,
                             __hip_bfloat16* __restrict__ Wt) {
    int tid = blockIdx.x * blockDim.x + threadIdx.x;   // 0..16383
    int n = tid & 127;
    int k = tid >> 7;
    Wt[n * 128 + k] = __float2bfloat16(W[k * 128 + n]);
}

// Kernel 2: Y = X @ W, bf16 out. 32 rows/block, 256 threads (4 waves).
// X staged fp32->bf16 into XOR-swizzled LDS (2-way max on b128 reads = free).
// MFMA swapped operands (A=Wt, B=X): lane's C-frag = 4 consecutive cols.
__global__ __launch_bounds__(256)
void gemm_kernel(const float* __restrict__ X,
                 const __hip_bfloat16* __restrict__ Wt,
                 char* __restrict__ Yb) {
    __shared__ unsigned short As[32 * 128];   // 8 KB, XOR-swizzled

    int tid = threadIdx.x;
    size_t rowbase = (size_t)blockIdx.x * 32;

    {
        int rr = tid >> 5;          // 0..7
        int c4 = (tid & 31) * 4;    // 0..124
        int kb = c4 >> 3;
        int ko = c4 & 7;
#pragma unroll
        for (int it = 0; it < 4; ++it) {
            int row = it * 8 + rr;
            // nontemporal: X is read exactly once; don't evict Yb from L2
            floatx4 f = __builtin_nontemporal_load(
                (const floatx4*)(X + (rowbase + row) * 128 + c4));
            uintx2 p;
            p.x = (unsigned)f2bf_u(f.x) | ((unsigned)f2bf_u(f.y) << 16);
            p.y = (unsigned)f2bf_u(f.z) | ((unsigned)f2bf_u(f.w) << 16);
            *(uintx2*)(As + row * 128 + ((kb ^ (row & 15)) << 3) + ko) = p;
        }
    }
    __syncthreads();

    int wv   = tid >> 6;
    int lane = tid & 63;
    int m16  = lane & 15;
    int quad = lane >> 4;
    int rt   = wv & 1;          // row-tile (16 rows)
    int ctb  = (wv >> 1) * 4;   // col-tile base

    floatx4 acc[4] = {{0,0,0,0},{0,0,0,0},{0,0,0,0},{0,0,0,0}};
    int arow = rt * 16 + m16;
#pragma unroll
    for (int s = 0; s < 4; ++s) {
        int kb = quad + s * 4;
        short8 bfrag = *(const short8*)(As + arow * 128 + ((kb ^ m16) << 3));
#pragma unroll
        for (int t = 0; t < 4; ++t) {
            short8 afrag = *(const short8*)(Wt + ((ctb + t) * 16 + m16) * 128 +
                                            quad * 8 + s * 32);
            acc[t] = __builtin_amdgcn_mfma_f32_16x16x32_bf16(afrag, bfrag,
                                                             acc[t], 0, 0, 0);
        }
    }

    size_t orow = rowbase + rt * 16 + m16;
#pragma unroll
    for (int t = 0; t < 4; ++t) {
        int ocol = (ctb + t) * 16 + quad * 4;
        uintx2 p;
        p.x = (unsigned)f2bf_u(acc[t][0]) | ((unsigned)f2bf_u(acc[t][1]) << 16);
        p.y = (unsigned)f2bf_u(acc[t][2]) | ((unsigned)f2bf_u(acc[t][3]) << 16);
        *(uintx2*)(Yb + orow * 256 + ocol * 2) = p;
    }
}

// Kernel 3: out[r,:] = sum_{e in row r} Yb[col[e],:]  (fp32 accumulate).
// 1 wave/row, 4 rows/block. 4 edges per gather instruction: edge slot
// sub = lane>>4, 16 lanes x uintx4(16B) = one full 256B row per quarter-wave.
// 16 edges per iter, masked single-iteration epilogue (no serial tail).
__global__ __launch_bounds__(256)
void agg_kernel(const char* __restrict__ Yb,
                const int* __restrict__ row_pointers,
                const int* __restrict__ column_index,
                float* __restrict__ out) {
    int tid  = threadIdx.x;
    int lane = tid & 63;
    int r    = blockIdx.x * 4 + (tid >> 6);
    int sub  = lane >> 4;          // edge slot 0..3
    int fo   = (lane & 15) * 16;   // byte offset within 256B row

    int e0 = row_pointers[r];
    int e1 = row_pointers[r + 1];

    floatx4 accA = {0.f, 0.f, 0.f, 0.f};
    floatx4 accB = {0.f, 0.f, 0.f, 0.f};

    int e = e0;
    int elast = e0 + ((e1 - e0) & ~15);
    for (; e < elast; e += 16) {
        int c0 = column_index[e + sub];
        int c1 = column_index[e + 4 + sub];
        int c2 = column_index[e + 8 + sub];
        int c3 = column_index[e + 12 + sub];
        uintx4 u0 = *(const uintx4*)(Yb + (size_t)c0 * 256 + fo);
        uintx4 u1 = *(const uintx4*)(Yb + (size_t)c1 * 256 + fo);
        uintx4 u2 = *(const uintx4*)(Yb + (size_t)c2 * 256 + fo);
        uintx4 u3 = *(const uintx4*)(Yb + (size_t)c3 * 256 + fo);
        acc_u4(accA, accB, u0);
        acc_u4(accA, accB, u1);
        acc_u4(accA, accB, u2);
        acc_u4(accA, accB, u3);
    }
    if (e < e1) {
        // masked epilogue: up to 15 edges, fully parallel, exec-masked per
        // quarter-wave (validity is uniform within a 16-lane slot group)
#pragma unroll
        for (int g = 0; g < 4; ++g) {
            int idx = e + g * 4 + sub;
            if (idx < e1) {
                int c = column_index[idx];
                uintx4 u = *(const uintx4*)(Yb + (size_t)c * 256 + fo);
                acc_u4(accA, accB, u);
            }
        }
    }

    // reduce across the 4 edge slots (xor-16, xor-32)
#pragma unroll
    for (int m = 16; m <= 32; m <<= 1) {
        accA.x += __shfl_xor(accA.x, m);
        accA.y += __shfl_xor(accA.y, m);
        accA.z += __shfl_xor(accA.z, m);
        accA.w += __shfl_xor(accA.w, m);
        accB.x += __shfl_xor(accB.x, m);
        accB.y += __shfl_xor(accB.y, m);
        accB.z += __shfl_xor(accB.z, m);
        accB.w += __shfl_xor(accB.w, m);
    }

    if (sub == 0) {
        float* dst = out + (size_t)r * 128 + (lane & 15) * 8;
        __builtin_nontemporal_store(accA, (floatx4*)dst);
        __builtin_nontemporal_store(accB, (floatx4*)(dst + 4));
    }
}

extern "C" void kernel_launch(void* const* d_in, const int* in_sizes, int n_in,
                              void* d_out, int out_size, void* d_ws, size_t ws_size,
                              hipStream_t stream) {
    const float* X       = (const float*)d_in[0];   // [N, 128] fp32
    const float* W       = (const float*)d_in[1];   // [128, 128] fp32
    const int* row_ptrs  = (const int*)d_in[2];     // [N+1]
    const int* col_index = (const int*)d_in[3];     // [E]

    float* out = (float*)d_out;
    const int N = in_sizes[2] - 1;                  // 100000

    char* ws = (char*)d_ws;
    __hip_bfloat16* Wt = (__hip_bfloat16*)ws;       // 32 KB
    char* Yb = ws + 32768;                          // N*128 bf16 = 25.6 MB

    wprep_kernel<<<64, 256, 0, stream>>>(W, Wt);
    gemm_kernel<<<N / 32, 256, 0, stream>>>(X, Wt, Yb);           // N=3125*32
    agg_kernel<<<N / 4, 256, 0, stream>>>(Yb, row_ptrs, col_index, out);
}